// Round 3
// baseline (865.076 us; speedup 1.0000x reference)
//
#include <hip/hip_runtime.h>
#include <math.h>

// Problem constants (fixed by setup_inputs)
static constexpr int Cc   = 16;   // C
static constexpr int COc  = 16;   // CO
static constexpr int Hh   = 4;    // heads
static constexpr int CHc  = 4;    // CO/H
static constexpr int CPWc = 32;   // 2*C
static constexpr int NTH  = 256;  // block size

typedef float f32x2 __attribute__((ext_vector_type(2)));
typedef float f32x4 __attribute__((ext_vector_type(4)));

// ---------------------------------------------------------------------------
// Kernel 1: per-row first-layer projections (validated rounds 1-2).
//   q rows: aW[r][j] = b1[j] + sum_i xq[i]*(w1[i][j]-w1[i+16][j])   (j<32)
//           aV[r][j] = bv1[j] + sum_i xq[i]*(v1[i][j]-v1[i+16][j])  (j<16)
//   k rows: cW[r][j] =          sum_i xk[i]*w1[i+16][j]
//           cV[r][j] =          sum_i xk[i]*v1[i+16][j]
// ---------------------------------------------------------------------------
__global__ __launch_bounds__(NTH) void ppa_precompute(
    const float* __restrict__ xq, const float* __restrict__ xk,
    const float* __restrict__ w1, const float* __restrict__ b1,
    const float* __restrict__ v1, const float* __restrict__ bv1,
    float* __restrict__ aW, float* __restrict__ aV,
    float* __restrict__ cW, float* __restrict__ cV,
    int BN, int BK) {
  __shared__ float sw1[CPWc * CPWc];  // 1024
  __shared__ float sv1[CPWc * COc];   // 512
  __shared__ float sb1[CPWc];
  __shared__ float sbv1[COc];
  const int t = threadIdx.x;
  for (int i = t; i < CPWc * CPWc; i += NTH) sw1[i] = w1[i];
  for (int i = t; i < CPWc * COc; i += NTH) sv1[i] = v1[i];
  if (t < CPWc) sb1[t] = b1[t];
  if (t < COc) sbv1[t] = bv1[t];
  __syncthreads();

  const int r = blockIdx.x * NTH + t;
  if (r >= BN + BK) return;
  const bool isQ = (r < BN);
  const int rr = isQ ? r : (r - BN);
  const float* src = isQ ? (xq + (size_t)rr * Cc) : (xk + (size_t)rr * Cc);

  float x[Cc];
#pragma unroll
  for (int i = 0; i < Cc; i += 4) {
    float4 v = *reinterpret_cast<const float4*>(src + i);
    x[i] = v.x; x[i + 1] = v.y; x[i + 2] = v.z; x[i + 3] = v.w;
  }

  if (isQ) {
#pragma unroll
    for (int j = 0; j < CPWc; ++j) {
      float acc = sb1[j];
#pragma unroll
      for (int i = 0; i < Cc; ++i)
        acc += x[i] * (sw1[i * CPWc + j] - sw1[(i + Cc) * CPWc + j]);
      aW[(size_t)rr * CPWc + j] = acc;
    }
#pragma unroll
    for (int j = 0; j < COc; ++j) {
      float acc = sbv1[j];
#pragma unroll
      for (int i = 0; i < Cc; ++i)
        acc += x[i] * (sv1[i * COc + j] - sv1[(i + Cc) * COc + j]);
      aV[(size_t)rr * COc + j] = acc;
    }
  } else {
#pragma unroll
    for (int j = 0; j < CPWc; ++j) {
      float acc = 0.f;
#pragma unroll
      for (int i = 0; i < Cc; ++i) acc += x[i] * sw1[(i + Cc) * CPWc + j];
      cW[(size_t)rr * CPWc + j] = acc;
    }
#pragma unroll
    for (int j = 0; j < COc; ++j) {
      float acc = 0.f;
#pragma unroll
      for (int i = 0; i < Cc; ++i) acc += x[i] * sv1[(i + Cc) * COc + j];
      cV[(size_t)rr * COc + j] = acc;
    }
  }
}

// ---------------------------------------------------------------------------
// Kernel 2: one block per (b,n) row; 256 threads; 4 k-iterations (Nk=1024).
// Logits are ReLU'd (>=0, O(1)) => plain exp-sum softmax (validated r1/r2).
// All row-uniform data (a, av, transposed weights, biases) stays in LDS
// (broadcast reads) -- NO readfirstlane (round-2 scratch catastrophe) and
// no big uniform register arrays (round-1 VGPR=256).
// GEMMs accumulate packed (f32x2) along the reduction axis -> v_pk_fma_f32.
// ---------------------------------------------------------------------------
__global__ __launch_bounds__(NTH, 4) void ppa_main(
    const float* __restrict__ aW, const float* __restrict__ aV,
    const float* __restrict__ cW, const float* __restrict__ cV,
    const float* __restrict__ w2, const float* __restrict__ b2,
    const float* __restrict__ v2, const float* __restrict__ bv2,
    float* __restrict__ out, int N, int Nk) {
  __shared__ __align__(16) float sw2t[Hh][CPWc];   // w2^T  [4][32]
  __shared__ __align__(16) float sv2t[COc][COc];   // v2^T  [16][16]
  __shared__ __align__(16) float sa[CPWc];         // a row [32]
  __shared__ __align__(16) float sav[COc];         // av row [16]
  __shared__ __align__(16) float sbv2[COc];
  __shared__ __align__(16) float sred[4][Hh + COc];

  const int t = threadIdx.x;
  const int row = blockIdx.x;  // [0, B*N)
  const int b = row / N;

  {  // stage uniforms (transpose weights so reduction axis is contiguous)
    const int c = t >> 4, j16 = t & 15;
    sv2t[c][j16] = v2[j16 * COc + c];              // all 256 threads
    if (t < Hh * CPWc) sw2t[t >> 5][t & 31] = w2[(t & 31) * Hh + (t >> 5)];
    if (t < CPWc) sa[t] = aW[(size_t)row * CPWc + t];
    if (t < COc) { sav[t] = aV[(size_t)row * COc + t]; sbv2[t] = bv2[t]; }
  }
  __syncthreads();

  float b2r[Hh];
#pragma unroll
  for (int h = 0; h < Hh; ++h) b2r[h] = b2[h];  // uniform global -> s_load

  float l[Hh] = {0.f, 0.f, 0.f, 0.f};
  float o[COc];
#pragma unroll
  for (int c = 0; c < COc; ++c) o[c] = 0.f;

  const float* cWb = cW + (size_t)b * Nk * CPWc;
  const float* cVb = cV + (size_t)b * Nk * COc;
  const f32x4 zero4 = (f32x4)(0.f);

  for (int kk = 0; kk < Nk; kk += NTH) {
    const int k = kk + t;
    const float* pcw = cWb + (size_t)k * CPWc;
    const float* pcv = cVb + (size_t)k * COc;

    // ---- hw = relu(a + cW_k), kept packed: hw2[16] f32x2
    f32x2 hw2[CPWc / 2];
#pragma unroll
    for (int q = 0; q < CPWc / 4; ++q) {
      f32x4 cw = *reinterpret_cast<const f32x4*>(pcw + 4 * q);
      f32x4 aa = *reinterpret_cast<const f32x4*>(&sa[4 * q]);
      f32x4 s = __builtin_elementwise_max(aa + cw, zero4);
      hw2[2 * q] = s.xy;
      hw2[2 * q + 1] = s.zw;
    }

    // ---- logits: lg[h] = relu( sum_j hw[j]*w2t[h][j] + b2[h] ); p = exp(lg)
    float p[Hh];
#pragma unroll
    for (int h = 0; h < Hh; ++h) {
      f32x2 acc = (f32x2)(0.f);
#pragma unroll
      for (int q = 0; q < CPWc / 4; ++q) {
        f32x4 w = *reinterpret_cast<const f32x4*>(&sw2t[h][4 * q]);
        acc += hw2[2 * q] * w.xy;
        acc += hw2[2 * q + 1] * w.zw;
      }
      const float lg = fmaxf(acc.x + acc.y + b2r[h], 0.f);
      p[h] = __expf(lg);
      l[h] += p[h];
    }

    // ---- hv = relu(av + cV_k), packed: hv2[8]
    f32x2 hv2[COc / 2];
#pragma unroll
    for (int q = 0; q < COc / 4; ++q) {
      f32x4 cv = *reinterpret_cast<const f32x4*>(pcv + 4 * q);
      f32x4 vv = *reinterpret_cast<const f32x4*>(&sav[4 * q]);
      f32x4 s = __builtin_elementwise_max(vv + cv, zero4);
      hv2[2 * q] = s.xy;
      hv2[2 * q + 1] = s.zw;
    }

    // ---- val[c] = relu( sum_j hv[j]*v2t[c][j] + bv2[c] ); o[c] += p[h]*val
#pragma unroll
    for (int c = 0; c < COc; ++c) {
      f32x2 acc = (f32x2)(0.f);
#pragma unroll
      for (int q = 0; q < COc / 4; ++q) {
        f32x4 w = *reinterpret_cast<const f32x4*>(&sv2t[c][4 * q]);
        acc += hv2[2 * q] * w.xy;
        acc += hv2[2 * q + 1] * w.zw;
      }
      const float val = fmaxf(acc.x + acc.y + sbv2[c], 0.f);
      o[c] += p[c >> 2] * val;
    }
  }

  // ---- plain-sum reduction: wave butterfly, then cross-wave via LDS.
#pragma unroll
  for (int off = 1; off < 64; off <<= 1) {
#pragma unroll
    for (int h = 0; h < Hh; ++h) l[h] += __shfl_xor(l[h], off);
#pragma unroll
    for (int c = 0; c < COc; ++c) o[c] += __shfl_xor(o[c], off);
  }
  const int lane = t & 63;
  const int wid = t >> 6;
  if (lane == 0) {
#pragma unroll
    for (int h = 0; h < Hh; ++h) sred[wid][h] = l[h];
#pragma unroll
    for (int c = 0; c < COc; ++c) sred[wid][Hh + c] = o[c];
  }
  __syncthreads();

  if (t < COc) {
    const int h = t >> 2;
    float lsum = 0.f, osum = 0.f;
#pragma unroll
    for (int w = 0; w < 4; ++w) {
      lsum += sred[w][h];
      osum += sred[w][Hh + t];
    }
    out[(size_t)row * COc + t] = osum / lsum;
  }
}

// ---------------------------------------------------------------------------
extern "C" void kernel_launch(void* const* d_in, const int* in_sizes, int n_in,
                              void* d_out, int out_size, void* d_ws, size_t ws_size,
                              hipStream_t stream) {
  const float* xq  = (const float*)d_in[0];
  const float* xk  = (const float*)d_in[1];
  const float* w1  = (const float*)d_in[2];
  const float* b1  = (const float*)d_in[3];
  const float* w2  = (const float*)d_in[4];
  const float* b2  = (const float*)d_in[5];
  const float* v1  = (const float*)d_in[6];
  const float* bv1 = (const float*)d_in[7];
  const float* v2  = (const float*)d_in[8];
  const float* bv2 = (const float*)d_in[9];
  float* out = (float*)d_out;

  const int BN = in_sizes[0] / Cc;  // B*N  = 2048
  const int BK = in_sizes[1] / Cc;  // B*Nk = 2048
  const int B = 2;                  // fixed by setup_inputs
  const int N = BN / B;
  const int Nk = BK / B;

  float* ws = (float*)d_ws;
  float* aW = ws;                          // BN*32
  float* aV = aW + (size_t)BN * CPWc;      // BN*16
  float* cW = aV + (size_t)BN * COc;       // BK*32
  float* cV = cW + (size_t)BK * CPWc;      // BK*16

  const int totalRows = BN + BK;
  const int pgrid = (totalRows + NTH - 1) / NTH;
  ppa_precompute<<<pgrid, NTH, 0, stream>>>(xq, xk, w1, b1, v1, bv1,
                                            aW, aV, cW, cV, BN, BK);
  ppa_main<<<BN, NTH, 0, stream>>>(aW, aV, cW, cV, w2, b2, v2, bv2, out, N, Nk);
}

// Round 4
// 602.080 us; speedup vs baseline: 1.4368x; 1.4368x over previous
//
#include <hip/hip_runtime.h>
#include <math.h>

// Problem constants (fixed by setup_inputs)
static constexpr int Cc   = 16;   // C
static constexpr int COc  = 16;   // CO
static constexpr int Hh   = 4;    // heads
static constexpr int CHc  = 4;    // CO/H
static constexpr int CPWc = 32;   // 2*C
static constexpr int NTH  = 256;  // block size

// 16B loads only; immediately unpacked to scalar floats (round-1-proven
// codegen: no ext_vector locals -> no scratch demotion).
union F4 { float4 v; float f[4]; };

// ---------------------------------------------------------------------------
// Kernel 1: per-row first-layer projections (validated rounds 1-3).
//   q rows: aW[r][j] = b1[j] + sum_i xq[i]*(w1[i][j]-w1[i+16][j])   (j<32)
//           aV[r][j] = bv1[j] + sum_i xq[i]*(v1[i][j]-v1[i+16][j])  (j<16)
//   k rows: cW[r][j] =          sum_i xk[i]*w1[i+16][j]
//           cV[r][j] =          sum_i xk[i]*v1[i+16][j]
// ---------------------------------------------------------------------------
__global__ __launch_bounds__(NTH) void ppa_precompute(
    const float* __restrict__ xq, const float* __restrict__ xk,
    const float* __restrict__ w1, const float* __restrict__ b1,
    const float* __restrict__ v1, const float* __restrict__ bv1,
    float* __restrict__ aW, float* __restrict__ aV,
    float* __restrict__ cW, float* __restrict__ cV,
    int BN, int BK) {
  __shared__ float sw1[CPWc * CPWc];  // 1024
  __shared__ float sv1[CPWc * COc];   // 512
  __shared__ float sb1[CPWc];
  __shared__ float sbv1[COc];
  const int t = threadIdx.x;
  for (int i = t; i < CPWc * CPWc; i += NTH) sw1[i] = w1[i];
  for (int i = t; i < CPWc * COc; i += NTH) sv1[i] = v1[i];
  if (t < CPWc) sb1[t] = b1[t];
  if (t < COc) sbv1[t] = bv1[t];
  __syncthreads();

  const int r = blockIdx.x * NTH + t;
  if (r >= BN + BK) return;
  const bool isQ = (r < BN);
  const int rr = isQ ? r : (r - BN);
  const float* src = isQ ? (xq + (size_t)rr * Cc) : (xk + (size_t)rr * Cc);

  float x[Cc];
#pragma unroll
  for (int i = 0; i < Cc; i += 4) {
    float4 v = *reinterpret_cast<const float4*>(src + i);
    x[i] = v.x; x[i + 1] = v.y; x[i + 2] = v.z; x[i + 3] = v.w;
  }

  if (isQ) {
#pragma unroll
    for (int j = 0; j < CPWc; ++j) {
      float acc = sb1[j];
#pragma unroll
      for (int i = 0; i < Cc; ++i)
        acc += x[i] * (sw1[i * CPWc + j] - sw1[(i + Cc) * CPWc + j]);
      aW[(size_t)rr * CPWc + j] = acc;
    }
#pragma unroll
    for (int j = 0; j < COc; ++j) {
      float acc = sbv1[j];
#pragma unroll
      for (int i = 0; i < Cc; ++i)
        acc += x[i] * (sv1[i * COc + j] - sv1[(i + Cc) * COc + j]);
      aV[(size_t)rr * COc + j] = acc;
    }
  } else {
#pragma unroll
    for (int j = 0; j < CPWc; ++j) {
      float acc = 0.f;
#pragma unroll
      for (int i = 0; i < Cc; ++i) acc += x[i] * sw1[(i + Cc) * CPWc + j];
      cW[(size_t)rr * CPWc + j] = acc;
    }
#pragma unroll
    for (int j = 0; j < COc; ++j) {
      float acc = 0.f;
#pragma unroll
      for (int i = 0; i < Cc; ++i) acc += x[i] * sv1[(i + Cc) * COc + j];
      cV[(size_t)rr * COc + j] = acc;
    }
  }
}

// ---------------------------------------------------------------------------
// Kernel 2: one block per (b,n) row; 256 threads; 2 iterations of 2 k's per
// thread (Nk=1024). Plain exp-sum softmax (logits ReLU'd >= 0; validated).
// Uniforms (w2, v2 natural layout, a, av, bv2) in LDS, broadcast-read at
// point of use; each weight read amortized over the 2 k's. All locals are
// scalar floats with static indices (r3's ext_vector scratch trap avoided;
// r2's readfirstlane SGPR-spill trap avoided). launch_bounds(256,3):
// VGPR cap ~170 >> expected ~120 live, so no spill, 3 waves/SIMD.
// ---------------------------------------------------------------------------
__global__ __launch_bounds__(NTH, 3) void ppa_main(
    const float* __restrict__ aW, const float* __restrict__ aV,
    const float* __restrict__ cW, const float* __restrict__ cV,
    const float* __restrict__ w2, const float* __restrict__ b2,
    const float* __restrict__ v2, const float* __restrict__ bv2,
    float* __restrict__ out, int N, int Nk) {
  __shared__ __align__(16) float sw2[CPWc * Hh];   // [32][4] natural layout
  __shared__ __align__(16) float sv2[COc * COc];   // [16][16] natural layout
  __shared__ __align__(16) float sa[CPWc];
  __shared__ __align__(16) float sav[COc];
  __shared__ __align__(16) float sbv2[COc];
  __shared__ __align__(16) float sred[4][Hh + COc];

  const int t = threadIdx.x;
  const int row = blockIdx.x;  // [0, B*N)
  const int b = row / N;

  sv2[t] = v2[t];                       // NTH == 256 == 16*16
  if (t < CPWc * Hh) sw2[t] = w2[t];
  if (t < CPWc) sa[t] = aW[(size_t)row * CPWc + t];
  if (t < COc) { sav[t] = aV[(size_t)row * COc + t]; sbv2[t] = bv2[t]; }
  __syncthreads();

  // b2 is kernel-arg-uniform: compiler emits s_load -> SGPRs (4 values only).
  const float b20 = b2[0], b21 = b2[1], b22 = b2[2], b23 = b2[3];

  float l[Hh] = {0.f, 0.f, 0.f, 0.f};
  float o[COc];
#pragma unroll
  for (int c = 0; c < COc; ++c) o[c] = 0.f;

  const float* cWb = cW + (size_t)b * Nk * CPWc;
  const float* cVb = cV + (size_t)b * Nk * COc;

  for (int kk = 0; kk < Nk; kk += 2 * NTH) {
    const int k0 = kk + t;
    const int k1 = k0 + NTH;
    const float* pc0 = cWb + (size_t)k0 * CPWc;
    const float* pc1 = cWb + (size_t)k1 * CPWc;

    // ---- logits: lg = relu(a + cW_k) @ w2 + b2, streamed in 4-j blocks.
    float lg0[Hh], lg1[Hh];
    lg0[0] = b20; lg0[1] = b21; lg0[2] = b22; lg0[3] = b23;
    lg1[0] = b20; lg1[1] = b21; lg1[2] = b22; lg1[3] = b23;
#pragma unroll
    for (int q = 0; q < CPWc / 4; ++q) {
      F4 x0, x1, a4;
      x0.v = *reinterpret_cast<const float4*>(pc0 + 4 * q);
      x1.v = *reinterpret_cast<const float4*>(pc1 + 4 * q);
      a4.v = *reinterpret_cast<const float4*>(&sa[4 * q]);
#pragma unroll
      for (int jj = 0; jj < 4; ++jj) {
        const float hw0 = fmaxf(a4.f[jj] + x0.f[jj], 0.f);
        const float hw1 = fmaxf(a4.f[jj] + x1.f[jj], 0.f);
        F4 w;
        w.v = *reinterpret_cast<const float4*>(&sw2[(4 * q + jj) * Hh]);
#pragma unroll
        for (int h = 0; h < Hh; ++h) {
          lg0[h] += hw0 * w.f[h];
          lg1[h] += hw1 * w.f[h];
        }
      }
    }
    float p0[Hh], p1[Hh];
#pragma unroll
    for (int h = 0; h < Hh; ++h) {
      p0[h] = __expf(fmaxf(lg0[h], 0.f));
      p1[h] = __expf(fmaxf(lg1[h], 0.f));
      l[h] += p0[h] + p1[h];
    }

    // ---- values: val = relu(av + cV_k) @ v2 + bv2, streamed in 4-j blocks.
    const float* pv0 = cVb + (size_t)k0 * COc;
    const float* pv1 = cVb + (size_t)k1 * COc;
    float val0[COc], val1[COc];
#pragma unroll
    for (int c4 = 0; c4 < COc; c4 += 4) {
      F4 bb;
      bb.v = *reinterpret_cast<const float4*>(&sbv2[c4]);
#pragma unroll
      for (int cc = 0; cc < 4; ++cc) {
        val0[c4 + cc] = bb.f[cc];
        val1[c4 + cc] = bb.f[cc];
      }
    }
#pragma unroll
    for (int q = 0; q < COc / 4; ++q) {
      F4 y0, y1, av4;
      y0.v = *reinterpret_cast<const float4*>(pv0 + 4 * q);
      y1.v = *reinterpret_cast<const float4*>(pv1 + 4 * q);
      av4.v = *reinterpret_cast<const float4*>(&sav[4 * q]);
#pragma unroll
      for (int jj = 0; jj < 4; ++jj) {
        const float hv0 = fmaxf(av4.f[jj] + y0.f[jj], 0.f);
        const float hv1 = fmaxf(av4.f[jj] + y1.f[jj], 0.f);
        const int j = 4 * q + jj;
#pragma unroll
        for (int c4 = 0; c4 < COc; c4 += 4) {
          F4 w;
          w.v = *reinterpret_cast<const float4*>(&sv2[j * COc + c4]);
#pragma unroll
          for (int cc = 0; cc < 4; ++cc) {
            val0[c4 + cc] += hv0 * w.f[cc];
            val1[c4 + cc] += hv1 * w.f[cc];
          }
        }
      }
    }
#pragma unroll
    for (int c = 0; c < COc; ++c) {
      o[c] += p0[c >> 2] * fmaxf(val0[c], 0.f) +
              p1[c >> 2] * fmaxf(val1[c], 0.f);
    }
  }

  // ---- plain-sum reduction: wave butterfly, then cross-wave via LDS.
#pragma unroll
  for (int off = 1; off < 64; off <<= 1) {
#pragma unroll
    for (int h = 0; h < Hh; ++h) l[h] += __shfl_xor(l[h], off);
#pragma unroll
    for (int c = 0; c < COc; ++c) o[c] += __shfl_xor(o[c], off);
  }
  const int lane = t & 63;
  const int wid = t >> 6;
  if (lane == 0) {
#pragma unroll
    for (int h = 0; h < Hh; ++h) sred[wid][h] = l[h];
#pragma unroll
    for (int c = 0; c < COc; ++c) sred[wid][Hh + c] = o[c];
  }
  __syncthreads();

  if (t < COc) {
    const int h = t >> 2;
    float lsum = 0.f, osum = 0.f;
#pragma unroll
    for (int w = 0; w < 4; ++w) {
      lsum += sred[w][h];
      osum += sred[w][Hh + t];
    }
    out[(size_t)row * COc + t] = osum / lsum;
  }
}

// ---------------------------------------------------------------------------
extern "C" void kernel_launch(void* const* d_in, const int* in_sizes, int n_in,
                              void* d_out, int out_size, void* d_ws, size_t ws_size,
                              hipStream_t stream) {
  const float* xq  = (const float*)d_in[0];
  const float* xk  = (const float*)d_in[1];
  const float* w1  = (const float*)d_in[2];
  const float* b1  = (const float*)d_in[3];
  const float* w2  = (const float*)d_in[4];
  const float* b2  = (const float*)d_in[5];
  const float* v1  = (const float*)d_in[6];
  const float* bv1 = (const float*)d_in[7];
  const float* v2  = (const float*)d_in[8];
  const float* bv2 = (const float*)d_in[9];
  float* out = (float*)d_out;

  const int BN = in_sizes[0] / Cc;  // B*N  = 2048
  const int BK = in_sizes[1] / Cc;  // B*Nk = 2048
  const int B = 2;                  // fixed by setup_inputs
  const int N = BN / B;
  const int Nk = BK / B;

  float* ws = (float*)d_ws;
  float* aW = ws;                          // BN*32
  float* aV = aW + (size_t)BN * CPWc;      // BN*16
  float* cW = aV + (size_t)BN * COc;       // BK*32
  float* cV = cW + (size_t)BK * CPWc;      // BK*16

  const int totalRows = BN + BK;
  const int pgrid = (totalRows + NTH - 1) / NTH;
  ppa_precompute<<<pgrid, NTH, 0, stream>>>(xq, xk, w1, b1, v1, bv1,
                                            aW, aV, cW, cV, BN, BK);
  ppa_main<<<BN, NTH, 0, stream>>>(aW, aV, cW, cV, w2, b2, v2, bv2, out, N, Nk);
}

// Round 5
// 452.755 us; speedup vs baseline: 1.9107x; 1.3298x over previous
//
#include <hip/hip_runtime.h>
#include <math.h>

// Problem constants (fixed by setup_inputs)
static constexpr int Cc   = 16;   // C
static constexpr int COc  = 16;   // CO
static constexpr int Hh   = 4;    // heads
static constexpr int CHc  = 4;    // CO/H
static constexpr int CPWc = 32;   // 2*C
static constexpr int NTH  = 256;  // block size

// 16B loads only; immediately unpacked to scalar floats (round-1-proven
// codegen: no ext_vector locals -> no scratch demotion).
union F4 { float4 v; float f[4]; };

// ---------------------------------------------------------------------------
// Kernel 1: per-row first-layer projections (validated rounds 1-4).
// ---------------------------------------------------------------------------
__global__ __launch_bounds__(NTH) void ppa_precompute(
    const float* __restrict__ xq, const float* __restrict__ xk,
    const float* __restrict__ w1, const float* __restrict__ b1,
    const float* __restrict__ v1, const float* __restrict__ bv1,
    float* __restrict__ aW, float* __restrict__ aV,
    float* __restrict__ cW, float* __restrict__ cV,
    int BN, int BK) {
  __shared__ float sw1[CPWc * CPWc];  // 1024
  __shared__ float sv1[CPWc * COc];   // 512
  __shared__ float sb1[CPWc];
  __shared__ float sbv1[COc];
  const int t = threadIdx.x;
  for (int i = t; i < CPWc * CPWc; i += NTH) sw1[i] = w1[i];
  for (int i = t; i < CPWc * COc; i += NTH) sv1[i] = v1[i];
  if (t < CPWc) sb1[t] = b1[t];
  if (t < COc) sbv1[t] = bv1[t];
  __syncthreads();

  const int r = blockIdx.x * NTH + t;
  if (r >= BN + BK) return;
  const bool isQ = (r < BN);
  const int rr = isQ ? r : (r - BN);
  const float* src = isQ ? (xq + (size_t)rr * Cc) : (xk + (size_t)rr * Cc);

  float x[Cc];
#pragma unroll
  for (int i = 0; i < Cc; i += 4) {
    float4 v = *reinterpret_cast<const float4*>(src + i);
    x[i] = v.x; x[i + 1] = v.y; x[i + 2] = v.z; x[i + 3] = v.w;
  }

  if (isQ) {
#pragma unroll
    for (int j = 0; j < CPWc; ++j) {
      float acc = sb1[j];
#pragma unroll
      for (int i = 0; i < Cc; ++i)
        acc += x[i] * (sw1[i * CPWc + j] - sw1[(i + Cc) * CPWc + j]);
      aW[(size_t)rr * CPWc + j] = acc;
    }
#pragma unroll
    for (int j = 0; j < COc; ++j) {
      float acc = sbv1[j];
#pragma unroll
      for (int i = 0; i < Cc; ++i)
        acc += x[i] * (sv1[i * COc + j] - sv1[(i + Cc) * COc + j]);
      aV[(size_t)rr * COc + j] = acc;
    }
  } else {
#pragma unroll
    for (int j = 0; j < CPWc; ++j) {
      float acc = 0.f;
#pragma unroll
      for (int i = 0; i < Cc; ++i) acc += x[i] * sw1[(i + Cc) * CPWc + j];
      cW[(size_t)rr * CPWc + j] = acc;
    }
#pragma unroll
    for (int j = 0; j < COc; ++j) {
      float acc = 0.f;
#pragma unroll
      for (int i = 0; i < Cc; ++i) acc += x[i] * sv1[(i + Cc) * COc + j];
      cV[(size_t)rr * COc + j] = acc;
    }
  }
}

// ---------------------------------------------------------------------------
// Kernel 2: one block per (b,n) row; 256 threads; 2 iterations of 2 k's per
// thread (Nk=1024). Plain exp-sum softmax (logits ReLU'd >= 0; validated).
// Uniforms (w2, v2 natural layout, a, av, bv2) in LDS, broadcast-read at
// point of use; each weight read amortized over the 2 k's.
//
// LAUNCH-BOUNDS LAW (measured r1-r4): VGPR cap = 256 / min_waves_arg, NOT
// 512/arg. arg=3 capped at 84, arg=4 at 64 -> massive scratch spill (the
// 800 MB FETCH catastrophes). arg=2 -> cap 128, which fits the ~110-VGPR
// live set of this 2-k streamed loop and gives 4 waves/SIMD.
// ---------------------------------------------------------------------------
__global__ __launch_bounds__(NTH, 2) void ppa_main(
    const float* __restrict__ aW, const float* __restrict__ aV,
    const float* __restrict__ cW, const float* __restrict__ cV,
    const float* __restrict__ w2, const float* __restrict__ b2,
    const float* __restrict__ v2, const float* __restrict__ bv2,
    float* __restrict__ out, int N, int Nk) {
  __shared__ __align__(16) float sw2[CPWc * Hh];   // [32][4] natural layout
  __shared__ __align__(16) float sv2[COc * COc];   // [16][16] natural layout
  __shared__ __align__(16) float sa[CPWc];
  __shared__ __align__(16) float sav[COc];
  __shared__ __align__(16) float sbv2[COc];
  __shared__ __align__(16) float sred[4][Hh + COc];

  const int t = threadIdx.x;
  const int row = blockIdx.x;  // [0, B*N)
  const int b = row / N;

  sv2[t] = v2[t];                       // NTH == 256 == 16*16
  if (t < CPWc * Hh) sw2[t] = w2[t];
  if (t < CPWc) sa[t] = aW[(size_t)row * CPWc + t];
  if (t < COc) { sav[t] = aV[(size_t)row * COc + t]; sbv2[t] = bv2[t]; }
  __syncthreads();

  // b2 is kernel-arg-uniform: compiler emits s_load -> SGPRs (4 values only).
  const float b20 = b2[0], b21 = b2[1], b22 = b2[2], b23 = b2[3];

  float l[Hh] = {0.f, 0.f, 0.f, 0.f};
  float o[COc];
#pragma unroll
  for (int c = 0; c < COc; ++c) o[c] = 0.f;

  const float* cWb = cW + (size_t)b * Nk * CPWc;
  const float* cVb = cV + (size_t)b * Nk * COc;

#pragma unroll 1
  for (int kk = 0; kk < Nk; kk += 2 * NTH) {
    const int k0 = kk + t;
    const int k1 = k0 + NTH;
    const float* pc0 = cWb + (size_t)k0 * CPWc;
    const float* pc1 = cWb + (size_t)k1 * CPWc;

    // ---- logits: lg = relu(a + cW_k) @ w2 + b2, streamed in 4-j blocks.
    float lg0[Hh], lg1[Hh];
    lg0[0] = b20; lg0[1] = b21; lg0[2] = b22; lg0[3] = b23;
    lg1[0] = b20; lg1[1] = b21; lg1[2] = b22; lg1[3] = b23;
#pragma unroll
    for (int q = 0; q < CPWc / 4; ++q) {
      F4 x0, x1, a4;
      x0.v = *reinterpret_cast<const float4*>(pc0 + 4 * q);
      x1.v = *reinterpret_cast<const float4*>(pc1 + 4 * q);
      a4.v = *reinterpret_cast<const float4*>(&sa[4 * q]);
#pragma unroll
      for (int jj = 0; jj < 4; ++jj) {
        const float hw0 = fmaxf(a4.f[jj] + x0.f[jj], 0.f);
        const float hw1 = fmaxf(a4.f[jj] + x1.f[jj], 0.f);
        F4 w;
        w.v = *reinterpret_cast<const float4*>(&sw2[(4 * q + jj) * Hh]);
#pragma unroll
        for (int h = 0; h < Hh; ++h) {
          lg0[h] += hw0 * w.f[h];
          lg1[h] += hw1 * w.f[h];
        }
      }
    }
    float p0[Hh], p1[Hh];
#pragma unroll
    for (int h = 0; h < Hh; ++h) {
      p0[h] = __expf(fmaxf(lg0[h], 0.f));
      p1[h] = __expf(fmaxf(lg1[h], 0.f));
      l[h] += p0[h] + p1[h];
    }

    // ---- values: val = relu(av + cV_k) @ v2 + bv2, streamed in 4-j blocks.
    const float* pv0 = cVb + (size_t)k0 * COc;
    const float* pv1 = cVb + (size_t)k1 * COc;
    float val0[COc], val1[COc];
#pragma unroll
    for (int c4 = 0; c4 < COc; c4 += 4) {
      F4 bb;
      bb.v = *reinterpret_cast<const float4*>(&sbv2[c4]);
#pragma unroll
      for (int cc = 0; cc < 4; ++cc) {
        val0[c4 + cc] = bb.f[cc];
        val1[c4 + cc] = bb.f[cc];
      }
    }
#pragma unroll
    for (int q = 0; q < COc / 4; ++q) {
      F4 y0, y1, av4;
      y0.v = *reinterpret_cast<const float4*>(pv0 + 4 * q);
      y1.v = *reinterpret_cast<const float4*>(pv1 + 4 * q);
      av4.v = *reinterpret_cast<const float4*>(&sav[4 * q]);
#pragma unroll
      for (int jj = 0; jj < 4; ++jj) {
        const float hv0 = fmaxf(av4.f[jj] + y0.f[jj], 0.f);
        const float hv1 = fmaxf(av4.f[jj] + y1.f[jj], 0.f);
        const int j = 4 * q + jj;
#pragma unroll
        for (int c4 = 0; c4 < COc; c4 += 4) {
          F4 w;
          w.v = *reinterpret_cast<const float4*>(&sv2[j * COc + c4]);
#pragma unroll
          for (int cc = 0; cc < 4; ++cc) {
            val0[c4 + cc] += hv0 * w.f[cc];
            val1[c4 + cc] += hv1 * w.f[cc];
          }
        }
      }
    }
#pragma unroll
    for (int c = 0; c < COc; ++c) {
      o[c] += p0[c >> 2] * fmaxf(val0[c], 0.f) +
              p1[c >> 2] * fmaxf(val1[c], 0.f);
    }
  }

  // ---- plain-sum reduction: wave butterfly, then cross-wave via LDS.
#pragma unroll
  for (int off = 1; off < 64; off <<= 1) {
#pragma unroll
    for (int h = 0; h < Hh; ++h) l[h] += __shfl_xor(l[h], off);
#pragma unroll
    for (int c = 0; c < COc; ++c) o[c] += __shfl_xor(o[c], off);
  }
  const int lane = t & 63;
  const int wid = t >> 6;
  if (lane == 0) {
#pragma unroll
    for (int h = 0; h < Hh; ++h) sred[wid][h] = l[h];
#pragma unroll
    for (int c = 0; c < COc; ++c) sred[wid][Hh + c] = o[c];
  }
  __syncthreads();

  if (t < COc) {
    const int h = t >> 2;
    float lsum = 0.f, osum = 0.f;
#pragma unroll
    for (int w = 0; w < 4; ++w) {
      lsum += sred[w][h];
      osum += sred[w][Hh + t];
    }
    out[(size_t)row * COc + t] = osum / lsum;
  }
}

// ---------------------------------------------------------------------------
extern "C" void kernel_launch(void* const* d_in, const int* in_sizes, int n_in,
                              void* d_out, int out_size, void* d_ws, size_t ws_size,
                              hipStream_t stream) {
  const float* xq  = (const float*)d_in[0];
  const float* xk  = (const float*)d_in[1];
  const float* w1  = (const float*)d_in[2];
  const float* b1  = (const float*)d_in[3];
  const float* w2  = (const float*)d_in[4];
  const float* b2  = (const float*)d_in[5];
  const float* v1  = (const float*)d_in[6];
  const float* bv1 = (const float*)d_in[7];
  const float* v2  = (const float*)d_in[8];
  const float* bv2 = (const float*)d_in[9];
  float* out = (float*)d_out;

  const int BN = in_sizes[0] / Cc;  // B*N  = 2048
  const int BK = in_sizes[1] / Cc;  // B*Nk = 2048
  const int B = 2;                  // fixed by setup_inputs
  const int N = BN / B;
  const int Nk = BK / B;

  float* ws = (float*)d_ws;
  float* aW = ws;                          // BN*32
  float* aV = aW + (size_t)BN * CPWc;      // BN*16
  float* cW = aV + (size_t)BN * COc;       // BK*32
  float* cV = cW + (size_t)BK * CPWc;      // BK*16

  const int totalRows = BN + BK;
  const int pgrid = (totalRows + NTH - 1) / NTH;
  ppa_precompute<<<pgrid, NTH, 0, stream>>>(xq, xk, w1, b1, v1, bv1,
                                            aW, aV, cW, cV, BN, BK);
  ppa_main<<<BN, NTH, 0, stream>>>(aW, aV, cW, cV, w2, b2, v2, bv2, out, N, Nk);
}